// Round 1
// 337.444 us; speedup vs baseline: 1.0622x; 1.0622x over previous
//
#include <hip/hip_runtime.h>
#include <math.h>

#define CCH 192
#define BATCH 8
#define HWSZ 16384                    // 128*128
#define NPER (CCH * HWSZ)             // per-sample elements: 3,145,728
#define NTOT ((size_t)BATCH * NPER)   // 25,165,824
#define INV65535 (1.0f / 65535.0f)

// LUT: 8193 knots over d in [0,1], stride padded to 8196 floats (16B aligned)
#define TABN    8193
#define TABSTR  8196
#define TSCALE  (8192.0f / 65535.0f)

// ws layout (bytes):
//   [0)      uint mm[16]  (min[8] then ~max[8]; both min-encoded -> one 0xFF memset inits all)
//   [256)    float wtab[192*64]  (fallback path only)
//   [65536)  float table[192*8196]  (likelihood LUT, ~6.3 MB)
#define WS_WTAB_OFF_FLOATS 64
#define WS_TAB_OFF_BYTES   65536
#define WS_NEEDED (WS_TAB_OFF_BYTES + (size_t)CCH * TABSTR * 4)

#define RED_BLOCKS_PER_SAMPLE 192
#define MINMAX_BLOCKS (BATCH * RED_BLOCKS_PER_SAMPLE)   // 1536
#define TAB_BLOCKS (CCH * 33)                           // 6336

typedef float f4 __attribute__((ext_vector_type(4)));

// ---------- helpers ----------
__device__ __forceinline__ unsigned f2u_ord(float f) {
    unsigned u = __float_as_uint(f);
    return (u & 0x80000000u) ? ~u : (u | 0x80000000u);
}
__device__ __forceinline__ float u2f_ord(unsigned u) {
    return __uint_as_float((u & 0x80000000u) ? (u ^ 0x80000000u) : ~u);
}
__device__ __forceinline__ float fexp2(float x) { return __builtin_amdgcn_exp2f(x); }
__device__ __forceinline__ float frcp(float x)  { return __builtin_amdgcn_rcpf(x); }
__device__ __forceinline__ float ftanh(float x) {
    return 1.0f - 2.0f * frcp(fexp2(2.8853900817779268f * x) + 1.0f);
}
__device__ __forceinline__ float fsig(float x) {
    return frcp(1.0f + fexp2(-1.4426950408889634f * x));
}

// ---------- per-element MLP ----------
__device__ __forceinline__ float eval_mlp(float x, const float* W)
{
    float a0 = fmaf(W[0], x, W[33]);
    float a1 = fmaf(W[1], x, W[34]);
    float a2 = fmaf(W[2], x, W[35]);
    a0 = fmaf(W[46], ftanh(a0), a0);
    a1 = fmaf(W[47], ftanh(a1), a1);
    a2 = fmaf(W[48], ftanh(a2), a2);

    float c0 = fmaf(W[3], a0, fmaf(W[4],  a1, fmaf(W[5],  a2, W[36])));
    float c1 = fmaf(W[6], a0, fmaf(W[7],  a1, fmaf(W[8],  a2, W[37])));
    float c2 = fmaf(W[9], a0, fmaf(W[10], a1, fmaf(W[11], a2, W[38])));
    c0 = fmaf(W[49], ftanh(c0), c0);
    c1 = fmaf(W[50], ftanh(c1), c1);
    c2 = fmaf(W[51], ftanh(c2), c2);

    float d0 = fmaf(W[12], c0, fmaf(W[13], c1, fmaf(W[14], c2, W[39])));
    float d1 = fmaf(W[15], c0, fmaf(W[16], c1, fmaf(W[17], c2, W[40])));
    float d2 = fmaf(W[18], c0, fmaf(W[19], c1, fmaf(W[20], c2, W[41])));
    d0 = fmaf(W[52], ftanh(d0), d0);
    d1 = fmaf(W[53], ftanh(d1), d1);
    d2 = fmaf(W[54], ftanh(d2), d2);

    float e0 = fmaf(W[21], d0, fmaf(W[22], d1, fmaf(W[23], d2, W[42])));
    float e1 = fmaf(W[24], d0, fmaf(W[25], d1, fmaf(W[26], d2, W[43])));
    float e2 = fmaf(W[27], d0, fmaf(W[28], d1, fmaf(W[29], d2, W[44])));
    e0 = fmaf(W[55], ftanh(e0), e0);
    e1 = fmaf(W[56], ftanh(e1), e1);
    e2 = fmaf(W[57], ftanh(e2), e2);

    return fmaf(W[30], e0, fmaf(W[31], e1, fmaf(W[32], e2, W[45])));
}

__device__ __forceinline__ float eval_lik(float d, const float* W)
{
    float lo = eval_mlp(d - 0.5f, W);
    float up = eval_mlp(d + 0.5f, W);
    return fmaxf(fsig(up) - fsig(lo), 1e-9f);
}

// ---------- minmax block body (both min-encoded: mm[b]=min, mm[8+b]=~max) ----------
__device__ __forceinline__ void minmax_block(const float* __restrict__ x,
                                             unsigned* __restrict__ mm,
                                             int bid)
{
    int b   = bid / RED_BLOCKS_PER_SAMPLE;
    int blk = bid % RED_BLOCKS_PER_SAMPLE;
    const f4* xs = (const f4*)(x + (size_t)b * NPER);
    int base = blk * 4096;
    float mn = INFINITY, mx = -INFINITY;
    #pragma unroll
    for (int i = 0; i < 16; ++i) {
        f4 v = xs[base + i * 256 + threadIdx.x];
        mn = fminf(mn, fminf(fminf(v.x, v.y), fminf(v.z, v.w)));
        mx = fmaxf(mx, fmaxf(fmaxf(v.x, v.y), fmaxf(v.z, v.w)));
    }
    #pragma unroll
    for (int off = 32; off > 0; off >>= 1) {
        mn = fminf(mn, __shfl_down(mn, off, 64));
        mx = fmaxf(mx, __shfl_down(mx, off, 64));
    }
    __shared__ float smn[4], smx[4];
    int wave = threadIdx.x >> 6;
    if ((threadIdx.x & 63) == 0) { smn[wave] = mn; smx[wave] = mx; }
    __syncthreads();
    if (threadIdx.x == 0) {
        #pragma unroll
        for (int i = 1; i < 4; ++i) { mn = fminf(mn, smn[i]); mx = fmaxf(mx, smx[i]); }
        atomicMin(&mm[b],     f2u_ord(mn));
        atomicMin(&mm[8 + b], ~f2u_ord(mx));
    }
}

// ---------- kernel P (fused): minmax (blocks [0,1536)) + LUT build (blocks [1536,7872)) ----------
// Table blocks recompute the 58 per-channel weights cooperatively in LDS (replaces setup_kernel).
__global__ __launch_bounds__(256) void prep_kernel(
    const float* __restrict__ x, unsigned* __restrict__ mm,
    const float* __restrict__ m0, const float* __restrict__ b0,
    const float* __restrict__ m1, const float* __restrict__ b1,
    const float* __restrict__ m2, const float* __restrict__ b2,
    const float* __restrict__ m3, const float* __restrict__ b3,
    const float* __restrict__ m4, const float* __restrict__ b4,
    const float* __restrict__ f0, const float* __restrict__ f1,
    const float* __restrict__ f2, const float* __restrict__ f3,
    float* __restrict__ tab)
{
    if (blockIdx.x < MINMAX_BLOCKS) {
        minmax_block(x, mm, blockIdx.x);
        return;
    }
    int tb = blockIdx.x - MINMAX_BLOCKS;
    int c  = tb / 33;
    int jc = tb % 33;
    int t  = threadIdx.x;

    __shared__ float sW[58];
    if (t < 58) {
        float v;
        if (t < 33) {
            if      (t < 3)  v = m0[c * 3 + t];
            else if (t < 12) v = m1[c * 9 + t - 3];
            else if (t < 21) v = m2[c * 9 + t - 12];
            else if (t < 30) v = m3[c * 9 + t - 21];
            else             v = m4[c * 3 + t - 30];
            v = fmaxf(v, 0.f) + log1pf(expf(-fabsf(v)));   // softplus, same formula as before
        } else if (t < 46) {
            int i = t - 33;
            if      (i < 3)  v = b0[c * 3 + i];
            else if (i < 6)  v = b1[c * 3 + i - 3];
            else if (i < 9)  v = b2[c * 3 + i - 6];
            else if (i < 12) v = b3[c * 3 + i - 9];
            else             v = b4[c];
        } else {
            int i = t - 46;
            if      (i < 3)  v = f0[c * 3 + i];
            else if (i < 6)  v = f1[c * 3 + i - 3];
            else if (i < 9)  v = f2[c * 3 + i - 6];
            else             v = f3[c * 3 + i - 9];
            v = tanhf(v);
        }
        sW[t] = v;
    }
    __syncthreads();

    float W[58];
    #pragma unroll
    for (int i = 0; i < 58; ++i) W[i] = sW[i];

    int j = jc * 256 + t;
    if (j < TABN) {
        float d = (float)j * (1.0f / 8192.0f);
        tab[(size_t)c * TABSTR + j] = eval_lik(d, W);
    }
}

// ---------- kernel G: quantize + LDS-LUT lerp + nontemporal write ----------
// grid = 192 ch * 8 samples = 1536 blocks of 256 threads; one (b,c) plane each.
__global__ __launch_bounds__(256) void gather_kernel(const float* __restrict__ x,
                                                     const unsigned* __restrict__ mm,
                                                     const float* __restrict__ tab,
                                                     float* __restrict__ out)
{
    __shared__ __align__(16) float ltab[TABN + 3];   // ~32.8 KB

    int c = blockIdx.x >> 3;
    int b = blockIdx.x & 7;
    int t = threadIdx.x;

    // stage channel table: 2048 float4 over 256 threads = 8 iters + tail elem (cached reads)
    const f4* tsrc = (const f4*)(tab + (size_t)c * TABSTR);
    f4* tdst = (f4*)ltab;
    #pragma unroll
    for (int i = 0; i < 8; ++i) tdst[i * 256 + t] = tsrc[i * 256 + t];
    if (t == 0) ltab[8192] = tab[(size_t)c * TABSTR + 8192];
    __syncthreads();

    float mn = u2f_ord(mm[b]);
    float mx = u2f_ord(~mm[8 + b]);
    float scale = 65535.0f / (mx - mn + 1e-12f);

    size_t base = ((size_t)b * CCH + c) * HWSZ;
    const f4* xin = (const f4*)(x + base);
    f4* o0 = (f4*)(out + base);
    f4* o1 = (f4*)(out + NTOT + base);

    auto proc = [&](float xi, float& od, float& ol) {
        float kf   = rintf((xi - mn) * scale);
        od         = kf * INV65535;
        float tpos = kf * TSCALE;
        int   j    = (int)tpos;
        j = j > 8191 ? 8191 : j;
        float frac = tpos - (float)j;
        float t0 = ltab[j];
        float t1 = ltab[j + 1];
        ol = fmaxf(fmaf(frac, t1 - t0, t0), 1e-9f);
    };

    #pragma unroll
    for (int i = 0; i < 16; ++i) {
        f4 v = __builtin_nontemporal_load(&xin[i * 256 + t]);
        float in[4] = {v.x, v.y, v.z, v.w};
        float xd[4], lk[4];
        #pragma unroll
        for (int k = 0; k < 4; ++k) proc(in[k], xd[k], lk[k]);
        f4 vxd = {xd[0], xd[1], xd[2], xd[3]};
        f4 vlk = {lk[0], lk[1], lk[2], lk[3]};
        __builtin_nontemporal_store(vxd, &o0[i * 256 + t]);
        __builtin_nontemporal_store(vlk, &o1[i * 256 + t]);
    }
}

// ---------- fallback path (ws too small for LUT): old-style weight precompute ----------
__global__ void setup_kernel(const float* __restrict__ m0, const float* __restrict__ b0,
                             const float* __restrict__ m1, const float* __restrict__ b1,
                             const float* __restrict__ m2, const float* __restrict__ b2,
                             const float* __restrict__ m3, const float* __restrict__ b3,
                             const float* __restrict__ m4, const float* __restrict__ b4,
                             const float* __restrict__ f0, const float* __restrict__ f1,
                             const float* __restrict__ f2, const float* __restrict__ f3,
                             float* __restrict__ wtab)
{
    int t = threadIdx.x;
    if (t < CCH) {
        float* w = wtab + t * 64;
        #pragma unroll
        for (int i = 0; i < 3; ++i) { float v = m0[t*3+i]; w[i]    = fmaxf(v,0.f)+log1pf(expf(-fabsf(v))); }
        #pragma unroll
        for (int i = 0; i < 9; ++i) { float v = m1[t*9+i]; w[3+i]  = fmaxf(v,0.f)+log1pf(expf(-fabsf(v))); }
        #pragma unroll
        for (int i = 0; i < 9; ++i) { float v = m2[t*9+i]; w[12+i] = fmaxf(v,0.f)+log1pf(expf(-fabsf(v))); }
        #pragma unroll
        for (int i = 0; i < 9; ++i) { float v = m3[t*9+i]; w[21+i] = fmaxf(v,0.f)+log1pf(expf(-fabsf(v))); }
        #pragma unroll
        for (int i = 0; i < 3; ++i) { float v = m4[t*3+i]; w[30+i] = fmaxf(v,0.f)+log1pf(expf(-fabsf(v))); }
        #pragma unroll
        for (int i = 0; i < 3; ++i) w[33+i] = b0[t*3+i];
        #pragma unroll
        for (int i = 0; i < 3; ++i) w[36+i] = b1[t*3+i];
        #pragma unroll
        for (int i = 0; i < 3; ++i) w[39+i] = b2[t*3+i];
        #pragma unroll
        for (int i = 0; i < 3; ++i) w[42+i] = b3[t*3+i];
        w[45] = b4[t];
        #pragma unroll
        for (int i = 0; i < 3; ++i) w[46+i] = tanhf(f0[t*3+i]);
        #pragma unroll
        for (int i = 0; i < 3; ++i) w[49+i] = tanhf(f1[t*3+i]);
        #pragma unroll
        for (int i = 0; i < 3; ++i) w[52+i] = tanhf(f2[t*3+i]);
        #pragma unroll
        for (int i = 0; i < 3; ++i) w[55+i] = tanhf(f3[t*3+i]);
    }
}

__global__ __launch_bounds__(256) void ebott_main(const float* __restrict__ x,
                                                  const unsigned* __restrict__ mm,
                                                  const float* __restrict__ wtab,
                                                  float* __restrict__ out)
{
    int blk = blockIdx.x;
    int q   = blk & 3;
    int c   = (blk >> 2) % CCH;
    int b   = blk / (4 * CCH);

    float W[58];
    const float* w = wtab + c * 64;
    #pragma unroll
    for (int i = 0; i < 58; ++i) W[i] = w[i];

    float mn = u2f_ord(mm[b]);
    float mx = u2f_ord(~mm[8 + b]);
    float scale = 65535.0f / (mx - mn + 1e-12f);

    size_t base = (size_t)(b * CCH + c) * HWSZ + q * 4096;
    const f4* xin = (const f4*)(x + base);
    f4* o0 = (f4*)(out + base);
    f4* o1 = (f4*)(out + NTOT + base);
    int t = threadIdx.x;

    #pragma unroll
    for (int i = 0; i < 4; ++i) {
        f4 v = xin[i * 256 + t];
        float in[4] = {v.x, v.y, v.z, v.w};
        float xd[4], lk[4];
        #pragma unroll
        for (int k = 0; k < 4; ++k) {
            float d = rintf((in[k] - mn) * scale) * INV65535;
            xd[k] = d;
            lk[k] = eval_lik(d, W);
        }
        f4 vxd = {xd[0], xd[1], xd[2], xd[3]};
        f4 vlk = {lk[0], lk[1], lk[2], lk[3]};
        o0[i * 256 + t] = vxd;
        o1[i * 256 + t] = vlk;
    }
}

extern "C" void kernel_launch(void* const* d_in, const int* in_sizes, int n_in,
                              void* d_out, int out_size, void* d_ws, size_t ws_size,
                              hipStream_t stream)
{
    const float* x  = (const float*)d_in[0];
    const float* m0 = (const float*)d_in[1];
    const float* b0 = (const float*)d_in[2];
    const float* m1 = (const float*)d_in[3];
    const float* b1 = (const float*)d_in[4];
    const float* m2 = (const float*)d_in[5];
    const float* b2 = (const float*)d_in[6];
    const float* m3 = (const float*)d_in[7];
    const float* b3 = (const float*)d_in[8];
    const float* m4 = (const float*)d_in[9];
    const float* b4 = (const float*)d_in[10];
    const float* f0 = (const float*)d_in[11];
    const float* f1 = (const float*)d_in[12];
    const float* f2 = (const float*)d_in[13];
    const float* f3 = (const float*)d_in[14];

    unsigned* mm = (unsigned*)d_ws;
    float* wtab  = (float*)d_ws + WS_WTAB_OFF_FLOATS;
    float* tab   = (float*)((char*)d_ws + WS_TAB_OFF_BYTES);
    float* out   = (float*)d_out;

    // init the 16 atomic slots (both slots min-encoded, so 0xFF is the identity)
    hipMemsetAsync(d_ws, 0xFF, 64, stream);

    if (ws_size >= WS_NEEDED) {
        prep_kernel<<<MINMAX_BLOCKS + TAB_BLOCKS, 256, 0, stream>>>(
            x, mm, m0, b0, m1, b1, m2, b2, m3, b3, m4, b4, f0, f1, f2, f3, tab);
        gather_kernel<<<CCH * BATCH, 256, 0, stream>>>(x, mm, tab, out);
    } else {
        setup_kernel<<<1, 256, 0, stream>>>(m0, b0, m1, b1, m2, b2, m3, b3, m4, b4,
                                            f0, f1, f2, f3, wtab);
        // minmax only (no table blocks); tab pointer unused by these blocks
        prep_kernel<<<MINMAX_BLOCKS, 256, 0, stream>>>(
            x, mm, m0, b0, m1, b1, m2, b2, m3, b3, m4, b4, f0, f1, f2, f3, tab);
        ebott_main<<<BATCH * CCH * 4, 256, 0, stream>>>(x, mm, wtab, out);
    }
}

// Round 2
// 324.263 us; speedup vs baseline: 1.1053x; 1.0406x over previous
//
#include <hip/hip_runtime.h>
#include <math.h>

#define CCH 192
#define BATCH 8
#define HWSZ 16384                    // 128*128
#define NPER (CCH * HWSZ)             // per-sample elements: 3,145,728
#define NTOT ((size_t)BATCH * NPER)   // 25,165,824
#define INV65535 (1.0f / 65535.0f)

// LUT: 8193 knots over d in [0,1], stride padded to 8196 floats (16B aligned)
#define TABN    8193
#define TABSTR  8196
#define TSCALE  (8192.0f / 65535.0f)

// ws layout (bytes):
//   [256)    float pmn[1536]   per-block min partials   (ends 6400)
//   [8192)   float pmx[1536]   per-block max partials   (ends 14336)
//   [16384)  float wtab[192*64]  (fallback path only)   (ends 65536)
//   [65536)  float table[192*8196]  (likelihood LUT, ~6.3 MB)
#define WS_PMN_OFF_FLOATS  64      // byte 256
#define WS_PMX_OFF_FLOATS  2048    // byte 8192
#define WS_WTAB_OFF_FLOATS 4096    // byte 16384
#define WS_TAB_OFF_BYTES   65536
#define WS_NEEDED (WS_TAB_OFF_BYTES + (size_t)CCH * TABSTR * 4)

#define RED_BLOCKS_PER_SAMPLE 192
#define MINMAX_BLOCKS (BATCH * RED_BLOCKS_PER_SAMPLE)   // 1536
#define TAB_BLOCKS (CCH * 33)                           // 6336

typedef float f4 __attribute__((ext_vector_type(4)));

// ---------- helpers ----------
__device__ __forceinline__ float fexp2(float x) { return __builtin_amdgcn_exp2f(x); }
__device__ __forceinline__ float frcp(float x)  { return __builtin_amdgcn_rcpf(x); }
__device__ __forceinline__ float ftanh(float x) {
    return 1.0f - 2.0f * frcp(fexp2(2.8853900817779268f * x) + 1.0f);
}
__device__ __forceinline__ float fsig(float x) {
    return frcp(1.0f + fexp2(-1.4426950408889634f * x));
}

// ---------- per-element MLP ----------
__device__ __forceinline__ float eval_mlp(float x, const float* W)
{
    float a0 = fmaf(W[0], x, W[33]);
    float a1 = fmaf(W[1], x, W[34]);
    float a2 = fmaf(W[2], x, W[35]);
    a0 = fmaf(W[46], ftanh(a0), a0);
    a1 = fmaf(W[47], ftanh(a1), a1);
    a2 = fmaf(W[48], ftanh(a2), a2);

    float c0 = fmaf(W[3], a0, fmaf(W[4],  a1, fmaf(W[5],  a2, W[36])));
    float c1 = fmaf(W[6], a0, fmaf(W[7],  a1, fmaf(W[8],  a2, W[37])));
    float c2 = fmaf(W[9], a0, fmaf(W[10], a1, fmaf(W[11], a2, W[38])));
    c0 = fmaf(W[49], ftanh(c0), c0);
    c1 = fmaf(W[50], ftanh(c1), c1);
    c2 = fmaf(W[51], ftanh(c2), c2);

    float d0 = fmaf(W[12], c0, fmaf(W[13], c1, fmaf(W[14], c2, W[39])));
    float d1 = fmaf(W[15], c0, fmaf(W[16], c1, fmaf(W[17], c2, W[40])));
    float d2 = fmaf(W[18], c0, fmaf(W[19], c1, fmaf(W[20], c2, W[41])));
    d0 = fmaf(W[52], ftanh(d0), d0);
    d1 = fmaf(W[53], ftanh(d1), d1);
    d2 = fmaf(W[54], ftanh(d2), d2);

    float e0 = fmaf(W[21], d0, fmaf(W[22], d1, fmaf(W[23], d2, W[42])));
    float e1 = fmaf(W[24], d0, fmaf(W[25], d1, fmaf(W[26], d2, W[43])));
    float e2 = fmaf(W[27], d0, fmaf(W[28], d1, fmaf(W[29], d2, W[44])));
    e0 = fmaf(W[55], ftanh(e0), e0);
    e1 = fmaf(W[56], ftanh(e1), e1);
    e2 = fmaf(W[57], ftanh(e2), e2);

    return fmaf(W[30], e0, fmaf(W[31], e1, fmaf(W[32], e2, W[45])));
}

__device__ __forceinline__ float eval_lik(float d, const float* W)
{
    float lo = eval_mlp(d - 0.5f, W);
    float up = eval_mlp(d + 0.5f, W);
    return fmaxf(fsig(up) - fsig(lo), 1e-9f);
}

// ---------- minmax block body: write per-block partials (no init needed) ----------
__device__ __forceinline__ void minmax_block(const float* __restrict__ x,
                                             float* __restrict__ pmn,
                                             float* __restrict__ pmx,
                                             int bid)
{
    int b   = bid / RED_BLOCKS_PER_SAMPLE;
    int blk = bid % RED_BLOCKS_PER_SAMPLE;
    const f4* xs = (const f4*)(x + (size_t)b * NPER);
    int base = blk * 4096;
    float mn = INFINITY, mx = -INFINITY;
    #pragma unroll
    for (int i = 0; i < 16; ++i) {
        f4 v = xs[base + i * 256 + threadIdx.x];
        mn = fminf(mn, fminf(fminf(v.x, v.y), fminf(v.z, v.w)));
        mx = fmaxf(mx, fmaxf(fmaxf(v.x, v.y), fmaxf(v.z, v.w)));
    }
    #pragma unroll
    for (int off = 32; off > 0; off >>= 1) {
        mn = fminf(mn, __shfl_down(mn, off, 64));
        mx = fmaxf(mx, __shfl_down(mx, off, 64));
    }
    __shared__ float smn[4], smx[4];
    int wave = threadIdx.x >> 6;
    if ((threadIdx.x & 63) == 0) { smn[wave] = mn; smx[wave] = mx; }
    __syncthreads();
    if (threadIdx.x == 0) {
        #pragma unroll
        for (int i = 1; i < 4; ++i) { mn = fminf(mn, smn[i]); mx = fmaxf(mx, smx[i]); }
        pmn[bid] = mn;       // bid == b*192 + blk : sample-major layout
        pmx[bid] = mx;
    }
}

// ---------- kernel P (fused): minmax (blocks [0,1536)) + LUT build (blocks [1536,7872)) ----------
__global__ __launch_bounds__(256) void prep_kernel(
    const float* __restrict__ x,
    float* __restrict__ pmn, float* __restrict__ pmx,
    const float* __restrict__ m0, const float* __restrict__ b0,
    const float* __restrict__ m1, const float* __restrict__ b1,
    const float* __restrict__ m2, const float* __restrict__ b2,
    const float* __restrict__ m3, const float* __restrict__ b3,
    const float* __restrict__ m4, const float* __restrict__ b4,
    const float* __restrict__ f0, const float* __restrict__ f1,
    const float* __restrict__ f2, const float* __restrict__ f3,
    float* __restrict__ tab)
{
    if (blockIdx.x < MINMAX_BLOCKS) {
        minmax_block(x, pmn, pmx, blockIdx.x);
        return;
    }
    int tb = blockIdx.x - MINMAX_BLOCKS;
    int c  = tb / 33;
    int jc = tb % 33;
    int t  = threadIdx.x;

    __shared__ float sW[58];
    if (t < 58) {
        float v;
        if (t < 33) {
            if      (t < 3)  v = m0[c * 3 + t];
            else if (t < 12) v = m1[c * 9 + t - 3];
            else if (t < 21) v = m2[c * 9 + t - 12];
            else if (t < 30) v = m3[c * 9 + t - 21];
            else             v = m4[c * 3 + t - 30];
            v = fmaxf(v, 0.f) + log1pf(expf(-fabsf(v)));   // softplus
        } else if (t < 46) {
            int i = t - 33;
            if      (i < 3)  v = b0[c * 3 + i];
            else if (i < 6)  v = b1[c * 3 + i - 3];
            else if (i < 9)  v = b2[c * 3 + i - 6];
            else if (i < 12) v = b3[c * 3 + i - 9];
            else             v = b4[c];
        } else {
            int i = t - 46;
            if      (i < 3)  v = f0[c * 3 + i];
            else if (i < 6)  v = f1[c * 3 + i - 3];
            else if (i < 9)  v = f2[c * 3 + i - 6];
            else             v = f3[c * 3 + i - 9];
            v = tanhf(v);
        }
        sW[t] = v;
    }
    __syncthreads();

    float W[58];
    #pragma unroll
    for (int i = 0; i < 58; ++i) W[i] = sW[i];

    int j = jc * 256 + t;
    if (j < TABN) {
        float d = (float)j * (1.0f / 8192.0f);
        tab[(size_t)c * TABSTR + j] = eval_lik(d, W);
    }
}

// ---------- kernel G: one block per (channel, sample-pair); 768 blocks, 3/CU ----------
__global__ __launch_bounds__(256) void gather_kernel(const float* __restrict__ x,
                                                     const float* __restrict__ pmn,
                                                     const float* __restrict__ pmx,
                                                     const float* __restrict__ tab,
                                                     float* __restrict__ out)
{
    __shared__ __align__(16) float ltab[TABN + 3];   // ~32.8 KB
    __shared__ float red[4][4];

    int c  = blockIdx.x >> 2;      // 0..191
    int p  = blockIdx.x & 3;       // pair id
    int b0 = p;
    int b1 = p + 4;
    int t  = threadIdx.x;

    size_t base0 = ((size_t)b0 * CCH + c) * HWSZ;
    size_t base1 = ((size_t)b1 * CCH + c) * HWSZ;
    const f4* xin0 = (const f4*)(x + base0);
    const f4* xin1 = (const f4*)(x + base1);

    // prefetch iteration-0 of both planes (registers survive the barrier;
    // these HBM loads overlap the LUT staging + partial reduce below)
    f4 pf0 = __builtin_nontemporal_load(&xin0[t]);
    f4 pf1 = __builtin_nontemporal_load(&xin1[t]);

    // stage channel LUT: 2048 float4 over 256 threads + tail elem
    const f4* tsrc = (const f4*)(tab + (size_t)c * TABSTR);
    f4* tdst = (f4*)ltab;
    #pragma unroll
    for (int i = 0; i < 8; ++i) tdst[i * 256 + t] = tsrc[i * 256 + t];
    if (t == 0) ltab[8192] = tab[(size_t)c * TABSTR + 8192];

    // reduce the 192 per-block partials for both samples
    float mn0 = t < 192 ? pmn[b0 * RED_BLOCKS_PER_SAMPLE + t] :  INFINITY;
    float mx0 = t < 192 ? pmx[b0 * RED_BLOCKS_PER_SAMPLE + t] : -INFINITY;
    float mn1 = t < 192 ? pmn[b1 * RED_BLOCKS_PER_SAMPLE + t] :  INFINITY;
    float mx1 = t < 192 ? pmx[b1 * RED_BLOCKS_PER_SAMPLE + t] : -INFINITY;
    #pragma unroll
    for (int off = 32; off > 0; off >>= 1) {
        mn0 = fminf(mn0, __shfl_down(mn0, off, 64));
        mx0 = fmaxf(mx0, __shfl_down(mx0, off, 64));
        mn1 = fminf(mn1, __shfl_down(mn1, off, 64));
        mx1 = fmaxf(mx1, __shfl_down(mx1, off, 64));
    }
    int wave = t >> 6;
    if ((t & 63) == 0) {
        red[wave][0] = mn0; red[wave][1] = mx0;
        red[wave][2] = mn1; red[wave][3] = mx1;
    }
    __syncthreads();   // covers LUT staging + red[]

    mn0 = fminf(fminf(red[0][0], red[1][0]), fminf(red[2][0], red[3][0]));
    mx0 = fmaxf(fmaxf(red[0][1], red[1][1]), fmaxf(red[2][1], red[3][1]));
    mn1 = fminf(fminf(red[0][2], red[1][2]), fminf(red[2][2], red[3][2]));
    mx1 = fmaxf(fmaxf(red[0][3], red[1][3]), fmaxf(red[2][3], red[3][3]));
    float scale0 = 65535.0f / (mx0 - mn0 + 1e-12f);
    float scale1 = 65535.0f / (mx1 - mn1 + 1e-12f);

    auto proc = [&](float xi, float mn, float scale, float& od, float& ol) {
        float kf   = rintf((xi - mn) * scale);
        od         = kf * INV65535;
        float tpos = kf * TSCALE;
        int   j    = (int)tpos;
        j = j > 8191 ? 8191 : j;
        float frac = tpos - (float)j;
        float t0 = ltab[j];
        float t1 = ltab[j + 1];
        ol = fmaxf(fmaf(frac, t1 - t0, t0), 1e-9f);
    };

    auto plane = [&](const f4* xin, f4* o0, f4* o1, float mn, float scale, f4 pf) {
        #pragma unroll
        for (int i = 0; i < 16; ++i) {
            f4 v = (i == 0) ? pf : __builtin_nontemporal_load(&xin[i * 256 + t]);
            float in[4] = {v.x, v.y, v.z, v.w};
            float xd[4], lk[4];
            #pragma unroll
            for (int k = 0; k < 4; ++k) proc(in[k], mn, scale, xd[k], lk[k]);
            f4 vxd = {xd[0], xd[1], xd[2], xd[3]};
            f4 vlk = {lk[0], lk[1], lk[2], lk[3]};
            __builtin_nontemporal_store(vxd, &o0[i * 256 + t]);
            __builtin_nontemporal_store(vlk, &o1[i * 256 + t]);
        }
    };

    plane(xin0, (f4*)(out + base0), (f4*)(out + NTOT + base0), mn0, scale0, pf0);
    plane(xin1, (f4*)(out + base1), (f4*)(out + NTOT + base1), mn1, scale1, pf1);
}

// ---------- fallback path (ws too small for LUT) ----------
__global__ void setup_kernel(const float* __restrict__ m0, const float* __restrict__ b0,
                             const float* __restrict__ m1, const float* __restrict__ b1,
                             const float* __restrict__ m2, const float* __restrict__ b2,
                             const float* __restrict__ m3, const float* __restrict__ b3,
                             const float* __restrict__ m4, const float* __restrict__ b4,
                             const float* __restrict__ f0, const float* __restrict__ f1,
                             const float* __restrict__ f2, const float* __restrict__ f3,
                             float* __restrict__ wtab)
{
    int t = threadIdx.x;
    if (t < CCH) {
        float* w = wtab + t * 64;
        #pragma unroll
        for (int i = 0; i < 3; ++i) { float v = m0[t*3+i]; w[i]    = fmaxf(v,0.f)+log1pf(expf(-fabsf(v))); }
        #pragma unroll
        for (int i = 0; i < 9; ++i) { float v = m1[t*9+i]; w[3+i]  = fmaxf(v,0.f)+log1pf(expf(-fabsf(v))); }
        #pragma unroll
        for (int i = 0; i < 9; ++i) { float v = m2[t*9+i]; w[12+i] = fmaxf(v,0.f)+log1pf(expf(-fabsf(v))); }
        #pragma unroll
        for (int i = 0; i < 9; ++i) { float v = m3[t*9+i]; w[21+i] = fmaxf(v,0.f)+log1pf(expf(-fabsf(v))); }
        #pragma unroll
        for (int i = 0; i < 3; ++i) { float v = m4[t*3+i]; w[30+i] = fmaxf(v,0.f)+log1pf(expf(-fabsf(v))); }
        #pragma unroll
        for (int i = 0; i < 3; ++i) w[33+i] = b0[t*3+i];
        #pragma unroll
        for (int i = 0; i < 3; ++i) w[36+i] = b1[t*3+i];
        #pragma unroll
        for (int i = 0; i < 3; ++i) w[39+i] = b2[t*3+i];
        #pragma unroll
        for (int i = 0; i < 3; ++i) w[42+i] = b3[t*3+i];
        w[45] = b4[t];
        #pragma unroll
        for (int i = 0; i < 3; ++i) w[46+i] = tanhf(f0[t*3+i]);
        #pragma unroll
        for (int i = 0; i < 3; ++i) w[49+i] = tanhf(f1[t*3+i]);
        #pragma unroll
        for (int i = 0; i < 3; ++i) w[52+i] = tanhf(f2[t*3+i]);
        #pragma unroll
        for (int i = 0; i < 3; ++i) w[55+i] = tanhf(f3[t*3+i]);
    }
}

__global__ __launch_bounds__(256) void ebott_main(const float* __restrict__ x,
                                                  const float* __restrict__ pmn,
                                                  const float* __restrict__ pmx,
                                                  const float* __restrict__ wtab,
                                                  float* __restrict__ out)
{
    int blk = blockIdx.x;
    int q   = blk & 3;
    int c   = (blk >> 2) % CCH;
    int b   = blk / (4 * CCH);

    float W[58];
    const float* w = wtab + c * 64;
    #pragma unroll
    for (int i = 0; i < 58; ++i) W[i] = w[i];

    float mn = INFINITY, mx = -INFINITY;
    for (int i = 0; i < RED_BLOCKS_PER_SAMPLE; ++i) {
        mn = fminf(mn, pmn[b * RED_BLOCKS_PER_SAMPLE + i]);
        mx = fmaxf(mx, pmx[b * RED_BLOCKS_PER_SAMPLE + i]);
    }
    float scale = 65535.0f / (mx - mn + 1e-12f);

    size_t base = (size_t)(b * CCH + c) * HWSZ + q * 4096;
    const f4* xin = (const f4*)(x + base);
    f4* o0 = (f4*)(out + base);
    f4* o1 = (f4*)(out + NTOT + base);
    int t = threadIdx.x;

    #pragma unroll
    for (int i = 0; i < 4; ++i) {
        f4 v = xin[i * 256 + t];
        float in[4] = {v.x, v.y, v.z, v.w};
        float xd[4], lk[4];
        #pragma unroll
        for (int k = 0; k < 4; ++k) {
            float d = rintf((in[k] - mn) * scale) * INV65535;
            xd[k] = d;
            lk[k] = eval_lik(d, W);
        }
        f4 vxd = {xd[0], xd[1], xd[2], xd[3]};
        f4 vlk = {lk[0], lk[1], lk[2], lk[3]};
        o0[i * 256 + t] = vxd;
        o1[i * 256 + t] = vlk;
    }
}

extern "C" void kernel_launch(void* const* d_in, const int* in_sizes, int n_in,
                              void* d_out, int out_size, void* d_ws, size_t ws_size,
                              hipStream_t stream)
{
    const float* x  = (const float*)d_in[0];
    const float* m0 = (const float*)d_in[1];
    const float* b0 = (const float*)d_in[2];
    const float* m1 = (const float*)d_in[3];
    const float* b1 = (const float*)d_in[4];
    const float* m2 = (const float*)d_in[5];
    const float* b2 = (const float*)d_in[6];
    const float* m3 = (const float*)d_in[7];
    const float* b3 = (const float*)d_in[8];
    const float* m4 = (const float*)d_in[9];
    const float* b4 = (const float*)d_in[10];
    const float* f0 = (const float*)d_in[11];
    const float* f1 = (const float*)d_in[12];
    const float* f2 = (const float*)d_in[13];
    const float* f3 = (const float*)d_in[14];

    float* pmn  = (float*)d_ws + WS_PMN_OFF_FLOATS;
    float* pmx  = (float*)d_ws + WS_PMX_OFF_FLOATS;
    float* wtab = (float*)d_ws + WS_WTAB_OFF_FLOATS;
    float* tab  = (float*)((char*)d_ws + WS_TAB_OFF_BYTES);
    float* out  = (float*)d_out;

    if (ws_size >= WS_NEEDED) {
        prep_kernel<<<MINMAX_BLOCKS + TAB_BLOCKS, 256, 0, stream>>>(
            x, pmn, pmx, m0, b0, m1, b1, m2, b2, m3, b3, m4, b4, f0, f1, f2, f3, tab);
        gather_kernel<<<CCH * 4, 256, 0, stream>>>(x, pmn, pmx, tab, out);
    } else {
        setup_kernel<<<1, 256, 0, stream>>>(m0, b0, m1, b1, m2, b2, m3, b3, m4, b4,
                                            f0, f1, f2, f3, wtab);
        prep_kernel<<<MINMAX_BLOCKS, 256, 0, stream>>>(
            x, pmn, pmx, m0, b0, m1, b1, m2, b2, m3, b3, m4, b4, f0, f1, f2, f3, tab);
        ebott_main<<<BATCH * CCH * 4, 256, 0, stream>>>(x, pmn, pmx, wtab, out);
    }
}